// Round 2
// baseline (241.762 us; speedup 1.0000x reference)
//
#include <hip/hip_runtime.h>
#include <hip/hip_bf16.h>

// AtomPoolingLayer: M=512, N=128 atoms, F=512, HID=128. fp32 in, fp32 out.
// out[m,f] = sum_n sigmoid(relu(h[m,n,:]@W1+b1)@W2+b2) * h[m,n,f]
//
// R8: R6 (barriered) and R7 (barrier-free) both ~215us -> barriers were not
// the limiter. Shared trait: 72KiB LDS -> 2 blocks/CU -> 2 waves/SIMD; the
// per-wave serial chain (stage->fence->MFMA->gate->phase2) is latency-bound
// with too little TLP. R8: 512 threads / 8 waves per 64-atom block (8 atoms
// per wave, MFMA rows duplicated x2 - MFMA is cheap), f-reduction scratch
// overlaid on As (dead by then) so LDS stays ~64.3KiB -> still 2 blocks/CU
// but 16 waves/CU = 4 waves/SIMD. __launch_bounds__(512,4) caps VGPR at 128
// (B single-buffered; 4x TLP hides L1/L2 B-load latency instead of a reg
// double-buffer). Numerics/swizzles identical to R7.

typedef unsigned short u16;
typedef unsigned int u32;
typedef __bf16 bf16x8 __attribute__((ext_vector_type(8)));
typedef float f32x4 __attribute__((ext_vector_type(4)));
typedef float f32x2 __attribute__((ext_vector_type(2)));
typedef u32 u32x4 __attribute__((ext_vector_type(4)));

#define M_MOL 512
#define N_ATOM 128
#define F_DIM 512
#define HID_DIM 128
#define ABLK 64            // atoms per block
#define NBLK (M_MOL * 2)   // 1024 blocks

static __device__ __forceinline__ u16 f2bf(float x) {
  u32 u = __float_as_uint(x);
  u32 r = (u + 0x7fffu + ((u >> 16) & 1u)) >> 16;  // RNE
  return (u16)r;
}
// repack two fp32x4 -> bf16x8 by truncation (|rel err| <= 2^-8)
static __device__ __forceinline__ bf16x8 pack8(u32x4 a, u32x4 b) {
  u32x4 r;
  r[0] = (a[0] >> 16) | (a[1] & 0xffff0000u);
  r[1] = (a[2] >> 16) | (a[3] & 0xffff0000u);
  r[2] = (b[0] >> 16) | (b[1] & 0xffff0000u);
  r[3] = (b[2] >> 16) | (b[3] & 0xffff0000u);
  return __builtin_bit_cast(bf16x8, r);
}

// ---- Kernel 1: W1 fp32 [F=512][HID=128] -> W1Tt bf16 [ks][hid][32] ----
__global__ __launch_bounds__(256) void transpose_w1(const float* __restrict__ W1,
                                                    u16* __restrict__ W1Tt) {
  __shared__ float tile[64][65];
  const int k0 = blockIdx.x * 64;
  const int n0 = blockIdx.y * 64;
  const int t = threadIdx.x;
  #pragma unroll
  for (int i = 0; i < 16; ++i) {
    const int lin = i * 256 + t;
    const int lr = lin >> 6, lc = lin & 63;
    tile[lc][lr] = W1[(size_t)(k0 + lr) * HID_DIM + (n0 + lc)];
  }
  __syncthreads();
  #pragma unroll
  for (int i = 0; i < 16; ++i) {
    const int lin = i * 256 + t;
    const int wr = lin >> 6, wc = lin & 63;   // wr: hid idx, wc: k idx
    const int k = k0 + wc;
    W1Tt[(size_t)(k >> 5) * (HID_DIM * 32) + (size_t)(n0 + wr) * 32 + (k & 31)] =
        f2bf(tile[wr][wc]);
  }
}

// ---- Kernel 2: 64-atom partial pooling; 512 threads (8 waves) ----
// Each wave owns 8 atoms end-to-end; 16 waves/CU for latency hiding.
__global__ __launch_bounds__(512, 4) void pool_partial(
    const float* __restrict__ h, const u16* __restrict__ W1Tt,
    const float* __restrict__ b1, const float* __restrict__ W2,
    const float* __restrict__ b2, float* __restrict__ part) {
  // As: h tile bf16, 64 rows x 512 elems; 16-B chunk c of row r stored at
  // chunk position (c&~7)|((c^r)&7) -> conflict-free for all access modes.
  // Rows 8wv..+7 written AND read only by wave wv (lgkm fence, no barrier).
  // After phase 2 As is dead -> reused as red[8][512] f32 (16 KiB).
  __shared__ __align__(16) u16 As[ABLK * F_DIM];   // 64 KiB
  __shared__ float w_s[ABLK];                      // 256 B

  const int blk = blockIdx.x;
  const int tid = threadIdx.x;
  const int wv = tid >> 6;     // wave 0..7 -> atoms wv*8..+7
  const int lane = tid & 63;
  const int quad = lane >> 4;
  const int cl = lane & 15;

  u16* AsW = As + wv * (8 * F_DIM);

  // ---- Stage A (per-wave): 8 rows, one 2-KiB coalesced row per step ----
  {
    const float* hw = h + (size_t)blk * (ABLK * F_DIM) + (size_t)(wv * 8) * F_DIM;
    #pragma unroll
    for (int g = 0; g < 2; ++g) {
      u32x4 lo[4], hi[4];
      #pragma unroll
      for (int i2 = 0; i2 < 4; ++i2) {
        const int i = g * 4 + i2;
        const u32x4* src = (const u32x4*)(hw + (size_t)i * F_DIM) + 2 * lane;
        lo[i2] = src[0];
        hi[i2] = src[1];
      }
      #pragma unroll
      for (int i2 = 0; i2 < 4; ++i2) {
        const int i = g * 4 + i2;
        const int phys = (lane & ~7) | ((lane ^ i) & 7);   // (8wv+i)&7 == i
        *(bf16x8*)(AsW + i * F_DIM + phys * 8) = pack8(lo[i2], hi[i2]);
      }
    }
  }

  // B pointer: lane (cl,quad) reads B[hid=t*16+cl][k=quad*8..+7] of tile ks
  const u16* bg = W1Tt + cl * 32 + quad * 8;

  // wave-local LDS fence: stage-A ds_writes land before cross-lane reads.
  asm volatile("s_waitcnt lgkmcnt(0)" ::: "memory");
  __builtin_amdgcn_sched_barrier(0);

  // ---- Phase 1: T[atom][hid] = h @ W1, MFMA 16x16x32 bf16, no barriers ----
  f32x4 acc[8];
  #pragma unroll
  for (int t = 0; t < 8; ++t) acc[t] = (f32x4){0.f, 0.f, 0.f, 0.f};

  // A row = own atom (cl&7); lanes cl and cl^8 read same addr (broadcast).
  const u16* aBase = AsW + (cl & 7) * F_DIM;

  #pragma unroll
  for (int ks = 0; ks < 16; ++ks) {
    u32x4 bfr[8];
    #pragma unroll
    for (int t = 0; t < 8; ++t)
      bfr[t] = *(const u32x4*)(bg + (size_t)ks * (HID_DIM * 32) + t * 512);
    const int c = ks * 4 + quad;
    const int aphys = (c & ~7) | ((c ^ cl) & 7);   // row&7 == cl&7
    bf16x8 afr = *(const bf16x8*)(aBase + aphys * 8);
    #pragma unroll
    for (int t = 0; t < 8; ++t)
      acc[t] = __builtin_amdgcn_mfma_f32_16x16x32_bf16(
          afr, __builtin_bit_cast(bf16x8, bfr[t]), acc[t], 0, 0, 0);
  }

  // ---- Epilogue: w[atom] = sigmoid(relu(T+b1)@W2 + b2), wave-local ----
  // C/D: col(=hid-in-tile)=cl, row(=atom-in-16)=quad*4+r; rows 8..15 are
  // duplicates of 0..7 -> only quad<2 writes.
  float psum[4] = {0.f, 0.f, 0.f, 0.f};
  #pragma unroll
  for (int t = 0; t < 8; ++t) {
    const int hid = t * 16 + cl;
    const float b1v = b1[hid];
    const float w2v = W2[hid];
    #pragma unroll
    for (int r = 0; r < 4; ++r) {
      float tv = fmaxf(acc[t][r] + b1v, 0.f);
      psum[r] = fmaf(tv, w2v, psum[r]);
    }
  }
  #pragma unroll
  for (int off = 1; off < 16; off <<= 1)
    #pragma unroll
    for (int r = 0; r < 4; ++r)
      psum[r] += __shfl_xor(psum[r], off, 64);
  if (cl == 0 && quad < 2) {
    const float b2v = b2[0];
    #pragma unroll
    for (int r = 0; r < 4; ++r)
      w_s[wv * 8 + quad * 4 + r] = 1.f / (1.f + __expf(-(psum[r] + b2v)));
  }
  // wave-local broadcast fence for w_s
  asm volatile("s_waitcnt lgkmcnt(0)" ::: "memory");
  __builtin_amdgcn_sched_barrier(0);

  // ---- Phase 2: partial[f] = sum over own 8 atoms of w * h, from LDS ----
  float facc[8] = {0.f, 0.f, 0.f, 0.f, 0.f, 0.f, 0.f, 0.f};
  #pragma unroll
  for (int i = 0; i < 8; ++i) {
    const float wn = w_s[wv * 8 + i];
    const int phys = (lane & ~7) | ((lane ^ i) & 7);
    bf16x8 hv = *(const bf16x8*)(AsW + i * F_DIM + phys * 8);
    u32x4 uv = __builtin_bit_cast(u32x4, hv);
    #pragma unroll
    for (int j = 0; j < 4; ++j) {
      facc[2 * j]     = fmaf(wn, __uint_as_float(uv[j] << 16), facc[2 * j]);
      facc[2 * j + 1] = fmaf(wn, __uint_as_float(uv[j] & 0xffff0000u), facc[2 * j + 1]);
    }
  }

  // ---- Cross-wave f-reduction; scratch overlaid on As (dead now) ----
  float* red = (float*)As;            // red[8][512]
  __syncthreads();                    // all waves done reading As
  #pragma unroll
  for (int j = 0; j < 8; ++j) red[wv * F_DIM + lane * 8 + j] = facc[j];
  __syncthreads();

  {
    const int f = tid;                // 512 threads, 1 float each
    float o = 0.f;
    #pragma unroll
    for (int w = 0; w < 8; ++w) o += red[w * F_DIM + f];
    part[(size_t)blk * F_DIM + f] = o;
  }
}

// ---- Kernel 3: out[m] = part[2m] + part[2m+1] ----
__global__ __launch_bounds__(256) void reduce_out(const float* __restrict__ part,
                                                  float* __restrict__ out) {
  const int m = blockIdx.x;
  const int f = threadIdx.x * 2;
  f32x2 a = *(const f32x2*)(part + (size_t)(2 * m) * F_DIM + f);
  f32x2 b = *(const f32x2*)(part + (size_t)(2 * m + 1) * F_DIM + f);
  f32x2 o;
  o[0] = a[0] + b[0];
  o[1] = a[1] + b[1];
  *(f32x2*)(out + (size_t)m * F_DIM + f) = o;
}

extern "C" void kernel_launch(void* const* d_in, const int* in_sizes, int n_in,
                              void* d_out, int out_size, void* d_ws, size_t ws_size,
                              hipStream_t stream) {
  const float* h  = (const float*)d_in[0];   // [512,128,512] fp32
  const float* W1 = (const float*)d_in[1];   // [512,128] fp32
  const float* b1 = (const float*)d_in[2];   // [128] fp32
  const float* W2 = (const float*)d_in[3];   // [128,1] fp32
  const float* b2 = (const float*)d_in[4];   // [1] fp32
  float* out = (float*)d_out;                // [512,512] fp32

  u16* W1Tt = (u16*)d_ws;                                 // 128 KiB (tiled)
  float* part = (float*)((char*)d_ws + (size_t)HID_DIM * F_DIM * sizeof(u16));  // 2 MiB

  transpose_w1<<<dim3(8, 2), 256, 0, stream>>>(W1, W1Tt);
  pool_partial<<<NBLK, 512, 0, stream>>>(h, W1Tt, b1, W2, b2, part);
  reduce_out<<<M_MOL, 256, 0, stream>>>(part, out);
}

// Round 3
// 227.485 us; speedup vs baseline: 1.0628x; 1.0628x over previous
//
#include <hip/hip_runtime.h>
#include <hip/hip_bf16.h>

// AtomPoolingLayer: M=512, N=128 atoms, F=512, HID=128. fp32 in, fp32 out.
// out[m,f] = sum_n sigmoid(relu(h[m,n,:]@W1+b1)@W2+b2) * h[m,n,f]
//
// R9: R8's counters (pool: Mfma 6.6%, VALU 8.2%, HBM 9%, occ 40%) showed the
// monolithic stage->fence->GEMM->gate->phase2 block is latency-bound with all
// pipes idle; three schedule variants all plateaued. Also FETCH=66MB for a
// 134MB input -> h is ~50% Infinity-Cache resident. R9 deletes the coupled
// structure: two pure streaming passes, zero LDS, zero barriers, zero fences.
//   gate_pass:  w = sigmoid(relu(h@W1+b1)@W2+b2). MFMA A-frags loaded
//               DIRECTLY from global (lane reads its own 32B run of h),
//               A+B register double-buffered, waves fully independent.
//   weight_pass: out[m,f] = sum_n w*h, h re-streamed in fp32 (L3-hot after
//               pass 1; h fits in 256MiB L3). part/reduce_out deleted.
// w numerics bit-identical to R6-R8 (same pack8 + MFMA order); final sum now
// fp32*fp32 (more accurate than old bf16 phase-2).

typedef unsigned short u16;
typedef unsigned int u32;
typedef __bf16 bf16x8 __attribute__((ext_vector_type(8)));
typedef float f32x4 __attribute__((ext_vector_type(4)));
typedef float f32x2 __attribute__((ext_vector_type(2)));
typedef u32 u32x4 __attribute__((ext_vector_type(4)));

#define M_MOL 512
#define N_ATOM 128
#define F_DIM 512
#define HID_DIM 128

static __device__ __forceinline__ u16 f2bf(float x) {
  u32 u = __float_as_uint(x);
  u32 r = (u + 0x7fffu + ((u >> 16) & 1u)) >> 16;  // RNE
  return (u16)r;
}
// repack two fp32x4 -> bf16x8 by truncation (|rel err| <= 2^-8)
static __device__ __forceinline__ bf16x8 pack8(u32x4 a, u32x4 b) {
  u32x4 r;
  r[0] = (a[0] >> 16) | (a[1] & 0xffff0000u);
  r[1] = (a[2] >> 16) | (a[3] & 0xffff0000u);
  r[2] = (b[0] >> 16) | (b[1] & 0xffff0000u);
  r[3] = (b[2] >> 16) | (b[3] & 0xffff0000u);
  return __builtin_bit_cast(bf16x8, r);
}

// ---- Kernel 1: W1 fp32 [F=512][HID=128] -> W1Tt bf16 [ks][hid][32] ----
// k-tile-contiguous: tile ks (32 k-elems x 128 hid = 8 KiB) is contiguous.
__global__ __launch_bounds__(256) void transpose_w1(const float* __restrict__ W1,
                                                    u16* __restrict__ W1Tt) {
  __shared__ float tile[64][65];
  const int k0 = blockIdx.x * 64;
  const int n0 = blockIdx.y * 64;
  const int t = threadIdx.x;
  #pragma unroll
  for (int i = 0; i < 16; ++i) {
    const int lin = i * 256 + t;
    const int lr = lin >> 6, lc = lin & 63;
    tile[lc][lr] = W1[(size_t)(k0 + lr) * HID_DIM + (n0 + lc)];
  }
  __syncthreads();
  #pragma unroll
  for (int i = 0; i < 16; ++i) {
    const int lin = i * 256 + t;
    const int wr = lin >> 6, wc = lin & 63;   // wr: hid idx, wc: k idx
    const int k = k0 + wc;
    W1Tt[(size_t)(k >> 5) * (HID_DIM * 32) + (size_t)(n0 + wr) * 32 + (k & 31)] =
        f2bf(tile[wr][wc]);
  }
}

// ---- Kernel 2: gate pass. 1024 blocks x 256 thr; wave owns 16 h-rows ----
// No LDS, no barriers. Lane (cl,quad) loads A directly: h[row cl][k-run].
__global__ __launch_bounds__(256) void gate_pass(
    const float* __restrict__ h, const u16* __restrict__ W1Tt,
    const float* __restrict__ b1, const float* __restrict__ W2,
    const float* __restrict__ b2, float* __restrict__ wbuf) {
  const int tid = threadIdx.x;
  const int wv = tid >> 6;
  const int lane = tid & 63;
  const int quad = lane >> 4;
  const int cl = lane & 15;

  const int row0 = blockIdx.x * 64 + wv * 16;       // wave's 16 h-rows
  // A: lane reads its own row (cl); per ks the 32B run [ks*32+quad*8 .. +8)
  const u32x4* ap = (const u32x4*)(h + (size_t)(row0 + cl) * F_DIM) + quad * 2;
  // B: lane (cl,quad) reads W1Tt[ks][hid=t*16+cl][k=quad*8..+7]
  const u16* bg = W1Tt + cl * 32 + quad * 8;

  f32x4 acc[8];
  #pragma unroll
  for (int t = 0; t < 8; ++t) acc[t] = (f32x4){0.f, 0.f, 0.f, 0.f};

  u32x4 aC0 = ap[0], aC1 = ap[1];
  u32x4 bC[8];
  #pragma unroll
  for (int t = 0; t < 8; ++t) bC[t] = *(const u32x4*)(bg + t * 512);

  #pragma unroll
  for (int ks = 0; ks < 16; ++ks) {
    u32x4 aN0, aN1, bN[8];
    if (ks < 15) {                                   // prefetch next k-slice
      aN0 = ap[(ks + 1) * 8];
      aN1 = ap[(ks + 1) * 8 + 1];
      #pragma unroll
      for (int t = 0; t < 8; ++t)
        bN[t] = *(const u32x4*)(bg + (size_t)(ks + 1) * (HID_DIM * 32) + t * 512);
    }
    bf16x8 afr = pack8(aC0, aC1);
    #pragma unroll
    for (int t = 0; t < 8; ++t)
      acc[t] = __builtin_amdgcn_mfma_f32_16x16x32_bf16(
          afr, __builtin_bit_cast(bf16x8, bC[t]), acc[t], 0, 0, 0);
    aC0 = aN0; aC1 = aN1;
    #pragma unroll
    for (int t = 0; t < 8; ++t) bC[t] = bN[t];
  }

  // w[row] = sigmoid(relu(T+b1)@W2 + b2); C/D: col(hid%16)=cl, row=quad*4+r
  float psum[4] = {0.f, 0.f, 0.f, 0.f};
  #pragma unroll
  for (int t = 0; t < 8; ++t) {
    const int hid = t * 16 + cl;
    const float b1v = b1[hid];
    const float w2v = W2[hid];
    #pragma unroll
    for (int r = 0; r < 4; ++r) {
      float tv = fmaxf(acc[t][r] + b1v, 0.f);
      psum[r] = fmaf(tv, w2v, psum[r]);
    }
  }
  #pragma unroll
  for (int off = 1; off < 16; off <<= 1)
    #pragma unroll
    for (int r = 0; r < 4; ++r)
      psum[r] += __shfl_xor(psum[r], off, 64);
  if (cl == 0) {
    const float b2v = b2[0];
    #pragma unroll
    for (int r = 0; r < 4; ++r)
      wbuf[row0 + quad * 4 + r] = 1.f / (1.f + __expf(-(psum[r] + b2v)));
  }
}

// ---- Kernel 3: weighted sum. 512 blocks (1/molecule) x 256 thr ----
// out[m,f] = sum_n w[m,n] * h[m,n,f]; h is L3-hot from pass 1.
__global__ __launch_bounds__(256) void weight_pass(
    const float* __restrict__ h, const float* __restrict__ wbuf,
    float* __restrict__ out) {
  const int m = blockIdx.x;
  const int f0 = threadIdx.x * 2;
  const float* hm = h + (size_t)m * (N_ATOM * F_DIM);
  const float* wm = wbuf + (size_t)m * N_ATOM;

  float a0 = 0.f, a1 = 0.f;
  #pragma unroll 2
  for (int n0 = 0; n0 < N_ATOM; n0 += 8) {
    f32x2 v[8];
    #pragma unroll
    for (int j = 0; j < 8; ++j)
      v[j] = *(const f32x2*)(hm + (size_t)(n0 + j) * F_DIM + f0);
    #pragma unroll
    for (int j = 0; j < 8; ++j) {
      const float wn = wm[n0 + j];               // uniform -> s_load broadcast
      a0 = fmaf(wn, v[j][0], a0);
      a1 = fmaf(wn, v[j][1], a1);
    }
  }
  f32x2 o; o[0] = a0; o[1] = a1;
  *(f32x2*)(out + (size_t)m * F_DIM + f0) = o;
}

extern "C" void kernel_launch(void* const* d_in, const int* in_sizes, int n_in,
                              void* d_out, int out_size, void* d_ws, size_t ws_size,
                              hipStream_t stream) {
  const float* h  = (const float*)d_in[0];   // [512,128,512] fp32
  const float* W1 = (const float*)d_in[1];   // [512,128] fp32
  const float* b1 = (const float*)d_in[2];   // [128] fp32
  const float* W2 = (const float*)d_in[3];   // [128,1] fp32
  const float* b2 = (const float*)d_in[4];   // [1] fp32
  float* out = (float*)d_out;                // [512,512] fp32

  u16* W1Tt = (u16*)d_ws;                                   // 128 KiB
  float* wbuf = (float*)((char*)d_ws + (size_t)HID_DIM * F_DIM * sizeof(u16));  // 256 KiB

  transpose_w1<<<dim3(8, 2), 256, 0, stream>>>(W1, W1Tt);
  gate_pass<<<M_MOL * 2, 256, 0, stream>>>(h, W1Tt, b1, W2, b2, wbuf);
  weight_pass<<<M_MOL, 256, 0, stream>>>(h, wbuf, out);
}

// Round 4
// 226.020 us; speedup vs baseline: 1.0697x; 1.0065x over previous
//
#include <hip/hip_runtime.h>
#include <hip/hip_bf16.h>

// AtomPoolingLayer: M=512, N=128 atoms, F=512, HID=128. fp32 in, fp32 out.
// out[m,f] = sum_n sigmoid(relu(h[m,n,:]@W1+b1)@W2+b2) * h[m,n,f]
//
// R10: R7(no-barriers)=neutral, R8(more waves)=worse, R9(two-pass)=worse ->
// the cost R6 carries is h's LDS round-trip (global->LDS->regs for MFMA,
// LDS->regs again for phase 2) + generation structure. R10: h goes
// global->VGPR ONCE and never to LDS: a wave's 16x512 A-tile is just 64
// VGPR/lane (16x bf16x8); the same fragments feed MFMA (phase 1) and the
// weighted sum (phase 2, shfl_xor reduce over the cl axis - lane(cl,quad)
// keeps f=cl*32+quad*8+j at ks==cl, a perfect bijection). W1 (128KiB bf16)
// lives entirely in LDS, staged once per block -> no per-wave L2 B-traffic.
// 512 blocks (1/molecule) x 512 thr, 144.5KiB LDS (1 block/CU), 2 barriers
// total. A-addressing = R9 gate (verified), epilogue = R6 (verified) -> w
// bit-identical to all passing rounds.

typedef unsigned short u16;
typedef unsigned int u32;
typedef __bf16 bf16x8 __attribute__((ext_vector_type(8)));
typedef float f32x4 __attribute__((ext_vector_type(4)));
typedef u32 u32x4 __attribute__((ext_vector_type(4)));

#define M_MOL 512
#define N_ATOM 128
#define F_DIM 512
#define HID_DIM 128

static __device__ __forceinline__ u16 f2bf(float x) {
  u32 u = __float_as_uint(x);
  u32 r = (u + 0x7fffu + ((u >> 16) & 1u)) >> 16;  // RNE
  return (u16)r;
}
// repack two fp32x4 -> bf16x8 by truncation (|rel err| <= 2^-8)
static __device__ __forceinline__ bf16x8 pack8(u32x4 a, u32x4 b) {
  u32x4 r;
  r[0] = (a[0] >> 16) | (a[1] & 0xffff0000u);
  r[1] = (a[2] >> 16) | (a[3] & 0xffff0000u);
  r[2] = (b[0] >> 16) | (b[1] & 0xffff0000u);
  r[3] = (b[2] >> 16) | (b[3] & 0xffff0000u);
  return __builtin_bit_cast(bf16x8, r);
}

// ---- Kernel 1: W1 fp32 [F=512][HID=128] -> W1Tt bf16 [ks][hid][32] ----
// k-tile-contiguous: tile ks (32 k-elems x 128 hid = 8 KiB) is contiguous.
__global__ __launch_bounds__(256) void transpose_w1(const float* __restrict__ W1,
                                                    u16* __restrict__ W1Tt) {
  __shared__ float tile[64][65];
  const int k0 = blockIdx.x * 64;
  const int n0 = blockIdx.y * 64;
  const int t = threadIdx.x;
  #pragma unroll
  for (int i = 0; i < 16; ++i) {
    const int lin = i * 256 + t;
    const int lr = lin >> 6, lc = lin & 63;
    tile[lc][lr] = W1[(size_t)(k0 + lr) * HID_DIM + (n0 + lc)];
  }
  __syncthreads();
  #pragma unroll
  for (int i = 0; i < 16; ++i) {
    const int lin = i * 256 + t;
    const int wr = lin >> 6, wc = lin & 63;   // wr: hid idx, wc: k idx
    const int k = k0 + wc;
    W1Tt[(size_t)(k >> 5) * (HID_DIM * 32) + (size_t)(n0 + wr) * 32 + (k & 31)] =
        f2bf(tile[wr][wc]);
  }
}

// ---- Kernel 2: one molecule per block; 512 threads (8 waves x 16 rows) ----
// h: global->VGPR once. W1: fully LDS-resident. 2 barriers total.
__global__ __launch_bounds__(512, 2) void pool_mol(
    const float* __restrict__ h, const u16* __restrict__ W1Tt,
    const float* __restrict__ b1, const float* __restrict__ W2,
    const float* __restrict__ b2, float* __restrict__ out) {
  __shared__ u16 Bs[16 * HID_DIM * 32];   // 128 KiB: all of W1 (bf16, tiled)
  __shared__ float red[8][F_DIM];         // 16 KiB: cross-wave f-reduction
  __shared__ float w_s[N_ATOM];           // 512 B: per-atom gates

  const int m = blockIdx.x;
  const int tid = threadIdx.x;
  const int wv = tid >> 6;                // wave 0..7 -> rows wv*16..+15
  const int lane = tid & 63;
  const int quad = lane >> 4;
  const int cl = lane & 15;

  // ---- Stage B: 128 KiB linear copy W1Tt -> Bs (L2-hot after block 0) ----
  {
    const u32x4* src = (const u32x4*)W1Tt;  // 8192 16-B units
    u32x4* dst = (u32x4*)Bs;
    #pragma unroll
    for (int i = 0; i < 16; ++i)
      dst[i * 512 + tid] = src[i * 512 + tid];
  }

  // ---- A-tile: lane (cl,quad) holds row cl, k = ks*32+quad*8..+7 ----
  // (identical addressing to R9 gate_pass; issued before the barrier so the
  // HBM stream flies while Bs lands)
  const int row = wv * 16 + cl;
  const float* hr = h + ((size_t)m * N_ATOM + row) * F_DIM;
  const u32x4* ap = (const u32x4*)hr + quad * 2;
  bf16x8 ah[16];                          // 64 VGPRs: the wave's whole A-tile
  {
    u32x4 a32[32];                        // transient fp32
    #pragma unroll
    for (int ks = 0; ks < 16; ++ks) {
      a32[2 * ks]     = ap[ks * 8];
      a32[2 * ks + 1] = ap[ks * 8 + 1];
    }
    #pragma unroll
    for (int ks = 0; ks < 16; ++ks)
      ah[ks] = pack8(a32[2 * ks], a32[2 * ks + 1]);
  }
  __syncthreads();                        // barrier 1: Bs ready

  // ---- Phase 1: T[row][hid] = h @ W1, MFMA 16x16x32 bf16, B from LDS ----
  f32x4 acc[8];
  #pragma unroll
  for (int t = 0; t < 8; ++t) acc[t] = (f32x4){0.f, 0.f, 0.f, 0.f};

  #pragma unroll
  for (int ks = 0; ks < 16; ++ks) {
    const u16* bt = Bs + ks * (HID_DIM * 32) + cl * 32 + quad * 8;
    #pragma unroll
    for (int t = 0; t < 8; ++t) {
      bf16x8 bfr = *(const bf16x8*)(bt + t * 512);  // contiguous 1 KiB/wave
      acc[t] = __builtin_amdgcn_mfma_f32_16x16x32_bf16(ah[ks], bfr, acc[t], 0, 0, 0);
    }
  }

  // ---- Epilogue: w[row] = sigmoid(relu(T+b1)@W2 + b2)  (R6-identical) ----
  float psum[4] = {0.f, 0.f, 0.f, 0.f};
  #pragma unroll
  for (int t = 0; t < 8; ++t) {
    const int hid = t * 16 + cl;
    const float b1v = b1[hid];
    const float w2v = W2[hid];
    #pragma unroll
    for (int r = 0; r < 4; ++r) {
      float tv = fmaxf(acc[t][r] + b1v, 0.f);
      psum[r] = fmaf(tv, w2v, psum[r]);
    }
  }
  #pragma unroll
  for (int off = 1; off < 16; off <<= 1)
    #pragma unroll
    for (int r = 0; r < 4; ++r)
      psum[r] += __shfl_xor(psum[r], off, 64);
  if (cl == 0) {
    const float b2v = b2[0];
    #pragma unroll
    for (int r = 0; r < 4; ++r)
      w_s[wv * 16 + quad * 4 + r] = 1.f / (1.f + __expf(-(psum[r] + b2v)));
  }
  // wave-local fence: w_s slice written & read only by this wave
  asm volatile("s_waitcnt lgkmcnt(0)" ::: "memory");
  __builtin_amdgcn_sched_barrier(0);

  // ---- Phase 2: weighted sum over the wave's 16 rows, straight from ah ----
  // lane(cl,quad) contributes w[cl]*h[cl][f]; shfl_xor reduce over cl sums
  // the 16 rows; result for f=ks*32+quad*8+j kept by lanes with cl==ks.
  const float wn = w_s[wv * 16 + cl];
  float fout[8];
  #pragma unroll
  for (int ks = 0; ks < 16; ++ks) {
    u32x4 uv = __builtin_bit_cast(u32x4, ah[ks]);
    float p[8];
    #pragma unroll
    for (int j = 0; j < 4; ++j) {
      p[2 * j]     = wn * __uint_as_float(uv[j] << 16);
      p[2 * j + 1] = wn * __uint_as_float(uv[j] & 0xffff0000u);
    }
    #pragma unroll
    for (int off = 1; off < 16; off <<= 1)
      #pragma unroll
      for (int j = 0; j < 8; ++j)
        p[j] += __shfl_xor(p[j], off, 64);
    if (cl == ks) {
      #pragma unroll
      for (int j = 0; j < 8; ++j) fout[j] = p[j];
    }
  }

  // red[wv][cl*32 + quad*8 + j]: bijective over the wave's 64x8 lanes/values
  #pragma unroll
  for (int j = 0; j < 8; ++j) red[wv][cl * 32 + quad * 8 + j] = fout[j];
  __syncthreads();                        // barrier 2: red ready

  {
    const int f = tid;                    // 512 threads, 1 feature each
    float o = 0.f;
    #pragma unroll
    for (int w = 0; w < 8; ++w) o += red[w][f];
    out[(size_t)m * F_DIM + f] = o;
  }
}

extern "C" void kernel_launch(void* const* d_in, const int* in_sizes, int n_in,
                              void* d_out, int out_size, void* d_ws, size_t ws_size,
                              hipStream_t stream) {
  const float* h  = (const float*)d_in[0];   // [512,128,512] fp32
  const float* W1 = (const float*)d_in[1];   // [512,128] fp32
  const float* b1 = (const float*)d_in[2];   // [128] fp32
  const float* W2 = (const float*)d_in[3];   // [128,1] fp32
  const float* b2 = (const float*)d_in[4];   // [1] fp32
  float* out = (float*)d_out;                // [512,512] fp32

  u16* W1Tt = (u16*)d_ws;                    // 128 KiB

  transpose_w1<<<dim3(8, 2), 256, 0, stream>>>(W1, W1Tt);
  pool_mol<<<M_MOL, 512, 0, stream>>>(h, W1Tt, b1, W2, b2, out);
}

// Round 5
// 206.707 us; speedup vs baseline: 1.1696x; 1.0934x over previous
//
#include <hip/hip_runtime.h>
#include <hip/hip_bf16.h>

// AtomPoolingLayer: M=512, N=128 atoms, F=512, HID=128. fp32 in, fp32 out.
// out[m,f] = sum_n sigmoid(relu(h[m,n,:]@W1+b1)@W2+b2) * h[m,n,f]
//
// R11: R10 replay rows proved the kernel is execution-bound, not BW-bound
// (82us even with h cache-resident). LDS unit was the hidden serial hog:
// (a) un-swizzled Bs reads = 8-way conflict x 1024 b128/block (2.5M conflict
// cycles); (b) phase-2 shfl butterfly = 512 cross-lane ops/lane, offsets 4/8
// become ds_swizzle. R11 keeps R10's bones (h->VGPR once, molecule/block,
// direct out) and deletes the LDS hogs: B streams from global (L1/L2-hot,
// 3-deep static register pipeline, no stage barrier); phase 2 uses R6's
// verified conflict-free As path (lane write-throughs its packed chunks at
// pack time: 16 ds_writes + 16 ds_reads/lane vs 512 swizzles). Only barrier
// left is the final f-reduce. pack8/MFMA addressing/epilogue verbatim from
// verified rounds.

typedef unsigned short u16;
typedef unsigned int u32;
typedef __bf16 bf16x8 __attribute__((ext_vector_type(8)));
typedef float f32x4 __attribute__((ext_vector_type(4)));
typedef u32 u32x4 __attribute__((ext_vector_type(4)));

#define M_MOL 512
#define N_ATOM 128
#define F_DIM 512
#define HID_DIM 128

static __device__ __forceinline__ u16 f2bf(float x) {
  u32 u = __float_as_uint(x);
  u32 r = (u + 0x7fffu + ((u >> 16) & 1u)) >> 16;  // RNE
  return (u16)r;
}
// repack two fp32x4 -> bf16x8 by truncation (|rel err| <= 2^-8)
static __device__ __forceinline__ bf16x8 pack8(u32x4 a, u32x4 b) {
  u32x4 r;
  r[0] = (a[0] >> 16) | (a[1] & 0xffff0000u);
  r[1] = (a[2] >> 16) | (a[3] & 0xffff0000u);
  r[2] = (b[0] >> 16) | (b[1] & 0xffff0000u);
  r[3] = (b[2] >> 16) | (b[3] & 0xffff0000u);
  return __builtin_bit_cast(bf16x8, r);
}

// ---- Kernel 1: W1 fp32 [F=512][HID=128] -> W1Tt bf16 [ks][hid][32] ----
// k-tile-contiguous: tile ks (32 k-elems x 128 hid = 8 KiB) is contiguous.
__global__ __launch_bounds__(256) void transpose_w1(const float* __restrict__ W1,
                                                    u16* __restrict__ W1Tt) {
  __shared__ float tile[64][65];
  const int k0 = blockIdx.x * 64;
  const int n0 = blockIdx.y * 64;
  const int t = threadIdx.x;
  #pragma unroll
  for (int i = 0; i < 16; ++i) {
    const int lin = i * 256 + t;
    const int lr = lin >> 6, lc = lin & 63;
    tile[lc][lr] = W1[(size_t)(k0 + lr) * HID_DIM + (n0 + lc)];
  }
  __syncthreads();
  #pragma unroll
  for (int i = 0; i < 16; ++i) {
    const int lin = i * 256 + t;
    const int wr = lin >> 6, wc = lin & 63;   // wr: hid idx, wc: k idx
    const int k = k0 + wc;
    W1Tt[(size_t)(k >> 5) * (HID_DIM * 32) + (size_t)(n0 + wr) * 32 + (k & 31)] =
        f2bf(tile[wr][wc]);
  }
}

// ---- Kernel 2: one molecule per block; 512 threads (8 waves x 16 rows) ----
__global__ __launch_bounds__(512, 2) void pool_mol(
    const float* __restrict__ h, const u16* __restrict__ W1Tt,
    const float* __restrict__ b1, const float* __restrict__ W2,
    const float* __restrict__ b2, float* __restrict__ out) {
  // As: h bf16, 128 rows x 512; 16-B chunk c of row r at phys chunk
  // (c&~7)|((c^r)&7)  -> conflict-free phase-2 reads (R6-verified layout).
  __shared__ u16 As[N_ATOM * F_DIM];      // 128 KiB
  __shared__ float red[8][F_DIM];         // 16 KiB
  __shared__ float w_s[N_ATOM];           // 512 B

  const int m = blockIdx.x;
  const int tid = threadIdx.x;
  const int wv = tid >> 6;                // wave 0..7 -> rows wv*16..+15
  const int lane = tid & 63;
  const int quad = lane >> 4;
  const int cl = lane & 15;

  // ---- A loads: lane (cl,quad) owns row, k = ks*32+quad*8..+7 ----
  // all 32 16-B loads issued up front -> deep HBM stream immediately
  const int row = wv * 16 + cl;
  const float* hr = h + ((size_t)m * N_ATOM + row) * F_DIM;
  const u32x4* ap = (const u32x4*)hr + quad * 2;
  u32x4 a32[16][2];
  #pragma unroll
  for (int ks = 0; ks < 16; ++ks) {
    a32[ks][0] = ap[ks * 8];
    a32[ks][1] = ap[ks * 8 + 1];
  }

  // ---- B preload: tiles 0,1 (L1/L2-hot; lane = W1Tt[ks][hid=t*16+cl][k=quad*8..]) ----
  const u16* bg = W1Tt + cl * 32 + quad * 8;
  u32x4 bf[3][8];                         // statically indexed under full unroll
  #pragma unroll
  for (int p = 0; p < 2; ++p)
    #pragma unroll
    for (int t = 0; t < 8; ++t)
      bf[p][t] = *(const u32x4*)(bg + (size_t)p * (HID_DIM * 32) + t * 512);

  // ---- pack fp32->bf16 into ah (MFMA A-frags) + write-through to As ----
  bf16x8 ah[16];
  #pragma unroll
  for (int ks = 0; ks < 16; ++ks) {
    ah[ks] = pack8(a32[ks][0], a32[ks][1]);
    const int c = ks * 4 + quad;
    const int phys = (c & ~7) | ((c ^ cl) & 7);   // row&7 == cl&7
    *(bf16x8*)(As + row * F_DIM + phys * 8) = ah[ks];
  }

  // ---- Phase 1: T = h @ W1, MFMA 16x16x32 bf16; B 3-deep reg pipeline ----
  f32x4 acc[8];
  #pragma unroll
  for (int t = 0; t < 8; ++t) acc[t] = (f32x4){0.f, 0.f, 0.f, 0.f};

  #pragma unroll
  for (int ks = 0; ks < 16; ++ks) {
    if (ks < 14) {                        // prefetch tile ks+2
      #pragma unroll
      for (int t = 0; t < 8; ++t)
        bf[(ks + 2) % 3][t] =
            *(const u32x4*)(bg + (size_t)(ks + 2) * (HID_DIM * 32) + t * 512);
    }
    #pragma unroll
    for (int t = 0; t < 8; ++t)
      acc[t] = __builtin_amdgcn_mfma_f32_16x16x32_bf16(
          ah[ks], __builtin_bit_cast(bf16x8, bf[ks % 3][t]), acc[t], 0, 0, 0);
  }

  // ---- Epilogue: w[row] = sigmoid(relu(T+b1)@W2 + b2)  (verified) ----
  float psum[4] = {0.f, 0.f, 0.f, 0.f};
  #pragma unroll
  for (int t = 0; t < 8; ++t) {
    const int hid = t * 16 + cl;
    const float b1v = b1[hid];
    const float w2v = W2[hid];
    #pragma unroll
    for (int r = 0; r < 4; ++r) {
      float tv = fmaxf(acc[t][r] + b1v, 0.f);
      psum[r] = fmaf(tv, w2v, psum[r]);
    }
  }
  #pragma unroll
  for (int off = 1; off < 16; off <<= 1)
    #pragma unroll
    for (int r = 0; r < 4; ++r)
      psum[r] += __shfl_xor(psum[r], off, 64);
  if (cl == 0) {
    const float b2v = b2[0];
    #pragma unroll
    for (int r = 0; r < 4; ++r)
      w_s[wv * 16 + quad * 4 + r] = 1.f / (1.f + __expf(-(psum[r] + b2v)));
  }
  // wave-local fence: covers w_s write AND this wave's As write-through.
  asm volatile("s_waitcnt lgkmcnt(0)" ::: "memory");
  __builtin_amdgcn_sched_barrier(0);

  // ---- Phase 2: weighted sum over own 16 rows from As (R6-verified) ----
  float facc[8] = {0.f, 0.f, 0.f, 0.f, 0.f, 0.f, 0.f, 0.f};
  #pragma unroll 4
  for (int i = 0; i < 16; ++i) {
    const int r = wv * 16 + i;
    const float wn = w_s[r];
    const int phys = (lane & ~7) | ((lane ^ i) & 7);   // r&7 == i&7
    bf16x8 hv = *(const bf16x8*)(As + r * F_DIM + phys * 8);
    u32x4 uv = __builtin_bit_cast(u32x4, hv);
    #pragma unroll
    for (int j = 0; j < 4; ++j) {
      facc[2 * j]     = fmaf(wn, __uint_as_float(uv[j] << 16), facc[2 * j]);
      facc[2 * j + 1] = fmaf(wn, __uint_as_float(uv[j] & 0xffff0000u), facc[2 * j + 1]);
    }
  }

  // ---- Cross-wave f-reduction (the ONLY barrier) ----
  #pragma unroll
  for (int j = 0; j < 8; ++j) red[wv][lane * 8 + j] = facc[j];
  __syncthreads();

  {
    const int f = tid;                    // 512 threads, 1 feature each
    float o = 0.f;
    #pragma unroll
    for (int w = 0; w < 8; ++w) o += red[w][f];
    out[(size_t)m * F_DIM + f] = o;
  }
}

extern "C" void kernel_launch(void* const* d_in, const int* in_sizes, int n_in,
                              void* d_out, int out_size, void* d_ws, size_t ws_size,
                              hipStream_t stream) {
  const float* h  = (const float*)d_in[0];   // [512,128,512] fp32
  const float* W1 = (const float*)d_in[1];   // [512,128] fp32
  const float* b1 = (const float*)d_in[2];   // [128] fp32
  const float* W2 = (const float*)d_in[3];   // [128,1] fp32
  const float* b2 = (const float*)d_in[4];   // [1] fp32
  float* out = (float*)d_out;                // [512,512] fp32

  u16* W1Tt = (u16*)d_ws;                    // 128 KiB

  transpose_w1<<<dim3(8, 2), 256, 0, stream>>>(W1, W1Tt);
  pool_mol<<<M_MOL, 512, 0, stream>>>(h, W1Tt, b1, W2, b2, out);
}